// Round 7
// baseline (703.161 us; speedup 1.0000x reference)
//
#include <hip/hip_runtime.h>
#include <hip/hip_fp16.h>

namespace {
constexpr int NN   = 10000;   // nodes
constexpr int NE   = 640000;  // edges
constexpr int INC  = 128;     // input channels
constexpr int HIDC = 256;     // hidden channels
constexpr int OUTC = 10;      // output channels
constexpr int NG   = 64;      // graphs
constexpr int DCAP = 128;     // per-node edge-slot cap (deg mean 64, sigma 8 -> 8-sigma bound)
constexpr int NRG  = 8;       // dst ranges for build (XCD heuristic)
constexpr int RNG  = NN / NRG;      // 1250 nodes per range
constexpr int SLICES = 32;          // edge slices for build
constexpr int EPSL   = NE / SLICES; // 20000 edges per slice
constexpr int GRP  = 4;             // nodes per gather group (1 per wave)
constexpr int NGRP = NN / GRP;      // 2500 groups
constexpr int GBLK = 2048;          // gather grid (work-queue consumers)
}

typedef __attribute__((ext_vector_type(8))) _Float16 half8;
typedef __attribute__((ext_vector_type(4))) float f32x4;
typedef __attribute__((ext_vector_type(4))) ushort u16x4;

__device__ __forceinline__ ushort f2h(float f) { return __half_as_ushort(__float2half(f)); }
__device__ __forceinline__ float h2f(ushort u) { return __half2float(__ushort_as_half(u)); }

// actual XCD id (gfx950; HW-verified readable). Locality hint only:
// correctness below never depends on its value.
__device__ __forceinline__ int get_xcc() {
    int x;
    asm volatile("s_getreg_b32 %0, hwreg(HW_REG_XCC_ID)" : "=s"(x));
    return x & 7;
}

// ---- zero deg cursors + pooled accumulator + queue counters ----
__global__ __launch_bounds__(256) void zero_kernel(int* __restrict__ deg,
                                                   float* __restrict__ pooled,
                                                   int* __restrict__ qctr) {
    const int gt = blockIdx.x * 256 + threadIdx.x;
    const int gs = gridDim.x * 256;
    for (int i = gt; i < NN; i += gs) deg[i] = 0;
    for (int i = gt; i < NG * HIDC; i += gs) pooled[i] = 0.0f;
    if (gt < 32) qctr[gt] = 0;
}

// ---- build: dst-range-partitioned two-scan counting scatter (proven round 4) ----
__global__ __launch_bounds__(1024) void build_kernel(const int* __restrict__ ei,
                                                     const float* __restrict__ ew,
                                                     int* __restrict__ deg,
                                                     uint* __restrict__ erec,
                                                     const float* __restrict__ x,
                                                     ushort* __restrict__ xh,
                                                     const float* __restrict__ W1,
                                                     ushort* __restrict__ w1h,
                                                     const float* __restrict__ W2,
                                                     ushort* __restrict__ w2h,
                                                     const float* __restrict__ W3,
                                                     ushort* __restrict__ w3h) {
    __shared__ int hist[RNG];
    const int t = threadIdx.x;
    const int rx = blockIdx.x & (NRG - 1);
    const int s  = blockIdx.x >> 3;
    const int nlo = rx * RNG;
    const int ebase = s * EPSL;

    for (int i = t; i < RNG; i += 1024) hist[i] = 0;
    __syncthreads();

    for (int vi = t * 4; vi < EPSL; vi += 4096) {
        const int4 d4 = *(const int4*)(ei + NE + ebase + vi);
        int rl;
        rl = d4.x - nlo; if ((uint)rl < (uint)RNG) atomicAdd(&hist[rl], 1);
        rl = d4.y - nlo; if ((uint)rl < (uint)RNG) atomicAdd(&hist[rl], 1);
        rl = d4.z - nlo; if ((uint)rl < (uint)RNG) atomicAdd(&hist[rl], 1);
        rl = d4.w - nlo; if ((uint)rl < (uint)RNG) atomicAdd(&hist[rl], 1);
    }
    __syncthreads();

    for (int b = t; b < RNG; b += 1024) {
        const int c = hist[b];
        if (c > 0) hist[b] = atomicAdd(&deg[nlo + b], c);
    }
    __syncthreads();

    for (int vi = t * 4; vi < EPSL; vi += 4096) {
        const int4 s4 = *(const int4*)(ei + ebase + vi);
        const int4 d4 = *(const int4*)(ei + NE + ebase + vi);
        const float4 w4 = *(const float4*)(ew + ebase + vi);
        int rl;
        rl = d4.x - nlo;
        if ((uint)rl < (uint)RNG) {
            const int idx = atomicAdd(&hist[rl], 1);
            if (idx < DCAP) erec[((size_t)(nlo + rl) << 7) + idx] = ((uint)s4.x << 16) | f2h(w4.x);
        }
        rl = d4.y - nlo;
        if ((uint)rl < (uint)RNG) {
            const int idx = atomicAdd(&hist[rl], 1);
            if (idx < DCAP) erec[((size_t)(nlo + rl) << 7) + idx] = ((uint)s4.y << 16) | f2h(w4.y);
        }
        rl = d4.z - nlo;
        if ((uint)rl < (uint)RNG) {
            const int idx = atomicAdd(&hist[rl], 1);
            if (idx < DCAP) erec[((size_t)(nlo + rl) << 7) + idx] = ((uint)s4.z << 16) | f2h(w4.z);
        }
        rl = d4.w - nlo;
        if ((uint)rl < (uint)RNG) {
            const int idx = atomicAdd(&hist[rl], 1);
            if (idx < DCAP) erec[((size_t)(nlo + rl) << 7) + idx] = ((uint)s4.w << 16) | f2h(w4.w);
        }
    }

    // conversion tail: fp32 -> fp16 of x and W1/W2/W3 (grid-stride, all blocks)
    const int gt = blockIdx.x * 1024 + t;
    const int gs = 256 * 1024;
    {
        const int n4 = NN * INC / 4;
        for (int i = gt; i < n4; i += gs) {
            f32x4 v = __builtin_nontemporal_load((const f32x4*)x + i);
            u16x4 o;
#pragma unroll
            for (int j = 0; j < 4; j++) o[j] = f2h(v[j]);
            __builtin_nontemporal_store(o, (u16x4*)xh + i);
        }
    }
    {
        const int n4 = HIDC * INC / 4;
        for (int i = gt; i < n4; i += gs) {
            f32x4 v = __builtin_nontemporal_load((const f32x4*)W1 + i);
            u16x4 o;
#pragma unroll
            for (int j = 0; j < 4; j++) o[j] = f2h(v[j]);
            __builtin_nontemporal_store(o, (u16x4*)w1h + i);
        }
    }
    {
        const int n4 = HIDC * HIDC / 4;
        for (int i = gt; i < n4; i += gs) {
            f32x4 v = __builtin_nontemporal_load((const f32x4*)W2 + i);
            u16x4 o;
#pragma unroll
            for (int j = 0; j < 4; j++) o[j] = f2h(v[j]);
            __builtin_nontemporal_store(o, (u16x4*)w2h + i);
            f32x4 v3 = __builtin_nontemporal_load((const f32x4*)W3 + i);
            u16x4 o3;
#pragma unroll
            for (int j = 0; j < 4; j++) o3[j] = f2h(v3[j]);
            __builtin_nontemporal_store(o3, (u16x4*)w3h + i);
        }
    }
}

// ---- XCD-pinned work-queue gather. 64-ch slices; slice working set = 1.28 MB
// (L2-resident per XCD). Block serves slice (xcc % NSPLIT), pops 4-node groups
// from that slice's queue, steals from others when drained (correct under any
// block->XCD mapping). Wave = 1 node, 2 edges in flight via half-wave split. ----
template <int K, int NSPLIT>
__global__ __launch_bounds__(256) void gatherq_kernel(const int* __restrict__ deg,
                                                      const uint* __restrict__ erec,
                                                      const ushort* __restrict__ X,
                                                      ushort* __restrict__ out,
                                                      int* __restrict__ qctr) {
    constexpr int U = 8;   // edge-pairs per batch (16 edges in flight)
    __shared__ int sg;
    const int tid = threadIdx.x;
    const int wv = tid >> 6, lane = tid & 63;
    const int sub = lane >> 5;
    const int cl  = lane & 31;
    const int myq = get_xcc() & (NSPLIT - 1);

    for (int dq = 0; dq < NSPLIT; ++dq) {
        const int q = (myq + dq) & (NSPLIT - 1);
        const size_t coff = (size_t)q * 64 + cl * 2;
        const ushort* xr = X + coff;
        while (true) {
            __syncthreads();
            if (tid == 0) sg = atomicAdd(&qctr[q], 1);
            __syncthreads();
            const int g = sg;
            if (g >= NGRP) break;

            const int n = g * GRP + wv;
            const int d = min(deg[n], DCAP);
            const int beg = n << 7;

            float a0, a1;
            {
                const uint v = *(const uint*)(X + (size_t)n * K + coff);  // (1+eps)*x self
                a0 = sub ? 0.f : h2f((ushort)(v & 0xFFFFu));
                a1 = sub ? 0.f : h2f((ushort)(v >> 16));
            }

            int e = 0;
            for (; e + 2 * U <= d; e += 2 * U) {
                uint rec[U];
#pragma unroll
                for (int u = 0; u < U; u++)
                    rec[u] = __builtin_nontemporal_load(erec + beg + e + 2 * u + sub);
                uint v[U];
#pragma unroll
                for (int u = 0; u < U; u++)
                    v[u] = *(const uint*)(xr + (size_t)(rec[u] >> 16) * K);
#pragma unroll
                for (int u = 0; u < U; u++) {
                    const float w = h2f((ushort)(rec[u] & 0xFFFFu));
                    a0 += w * h2f((ushort)(v[u] & 0xFFFFu));
                    a1 += w * h2f((ushort)(v[u] >> 16));
                }
            }
            for (; e + 2 <= d; e += 2) {
                const uint rec = __builtin_nontemporal_load(erec + beg + e + sub);
                const float w = h2f((ushort)(rec & 0xFFFFu));
                const uint v = *(const uint*)(xr + (size_t)(rec >> 16) * K);
                a0 += w * h2f((ushort)(v & 0xFFFFu));
                a1 += w * h2f((ushort)(v >> 16));
            }
            if (e < d && sub == 0) {
                const uint rec = __builtin_nontemporal_load(erec + beg + e);
                const float w = h2f((ushort)(rec & 0xFFFFu));
                const uint v = *(const uint*)(xr + (size_t)(rec >> 16) * K);
                a0 += w * h2f((ushort)(v & 0xFFFFu));
                a1 += w * h2f((ushort)(v >> 16));
            }

            a0 += __shfl_xor(a0, 32, 64);
            a1 += __shfl_xor(a1, 32, 64);
            if (sub == 0) {
                const uint ob = (uint)f2h(a0) | ((uint)f2h(a1) << 16);
                __builtin_nontemporal_store(ob, (uint*)(out + (size_t)n * K + coff));
            }
        }
    }
}

// ---- MFMA fp16 GEMM: C[M,256] = relu(A[M,K] @ W[256,K]^T + bias), fp16 out ----
template <int K>
__global__ __launch_bounds__(256) void mfma_gemm_kernel(const ushort* __restrict__ A,
                                                        const ushort* __restrict__ Wb,
                                                        const float* __restrict__ bias,
                                                        ushort* __restrict__ C, int M) {
    constexpr int LDW = K + 8;
    __shared__ ushort Ws[64 * LDW];
    const int tid = threadIdx.x;
    const int bm = blockIdx.x * 128;
    const int bn = blockIdx.y * 64;

    constexpr int CPR = K / 8;
    for (int idx = tid; idx < 64 * CPR; idx += 256) {
        int r = idx / CPR, c = idx % CPR;
        uint4 v = *(const uint4*)(Wb + (size_t)(bn + r) * K + c * 8);
        *(uint4*)(&Ws[r * LDW + c * 8]) = v;
    }
    __syncthreads();

    const int wave = tid >> 6;
    const int lane = tid & 63;
    const int lrow = lane & 15;
    const int lq   = lane >> 4;
    const int m0 = bm + wave * 32;

    f32x4 acc[2][4] = {};
    const int r0 = min(m0 + lrow, M - 1);
    const int r1 = min(m0 + 16 + lrow, M - 1);

    for (int k0 = 0; k0 < K; k0 += 32) {
        const int kk = k0 + lq * 8;
        half8 a0 = __builtin_nontemporal_load((const half8*)(A + (size_t)r0 * K + kk));
        half8 a1 = __builtin_nontemporal_load((const half8*)(A + (size_t)r1 * K + kk));
        half8 b[4];
#pragma unroll
        for (int j = 0; j < 4; j++)
            b[j] = *(const half8*)(&Ws[(j * 16 + lrow) * LDW + kk]);
#pragma unroll
        for (int j = 0; j < 4; j++) {
            acc[0][j] = __builtin_amdgcn_mfma_f32_16x16x32_f16(a0, b[j], acc[0][j], 0, 0, 0);
            acc[1][j] = __builtin_amdgcn_mfma_f32_16x16x32_f16(a1, b[j], acc[1][j], 0, 0, 0);
        }
    }

#pragma unroll
    for (int sub = 0; sub < 2; sub++) {
#pragma unroll
        for (int j = 0; j < 4; j++) {
            const int gn = bn + j * 16 + lrow;
            const float bv = bias[gn];
#pragma unroll
            for (int i = 0; i < 4; i++) {
                const int gm = m0 + sub * 16 + lq * 4 + i;
                if (gm < M) {
                    float v = acc[sub][j][i] + bv;
                    v = fmaxf(v, 0.0f);
                    C[(size_t)gm * HIDC + gn] = f2h(v);
                }
            }
        }
    }
}

// ---- layer-3 GEMM with fused mean-pool numerators (no h store) ----
__global__ __launch_bounds__(256) void mfma_gemm_pool_kernel(const ushort* __restrict__ A,
                                                             const ushort* __restrict__ Wb,
                                                             const float* __restrict__ bias,
                                                             const int* __restrict__ batch,
                                                             float* __restrict__ pooled, int M) {
    constexpr int K = HIDC;
    constexpr int LDW = K + 8;
    __shared__ ushort Ws[64 * LDW];
    __shared__ float pl[6][64];
    const int tid = threadIdx.x;
    const int bm = blockIdx.x * 128;
    const int bn = blockIdx.y * 64;

    constexpr int CPR = K / 8;
    for (int idx = tid; idx < 64 * CPR; idx += 256) {
        int r = idx / CPR, c = idx % CPR;
        uint4 v = *(const uint4*)(Wb + (size_t)(bn + r) * K + c * 8);
        *(uint4*)(&Ws[r * LDW + c * 8]) = v;
    }
    for (int i = tid; i < 6 * 64; i += 256) pl[i >> 6][i & 63] = 0.0f;
    __syncthreads();

    const int wave = tid >> 6;
    const int lane = tid & 63;
    const int lrow = lane & 15;
    const int lq   = lane >> 4;
    const int m0 = bm + wave * 32;
    const int g0 = batch[bm];

    f32x4 acc[2][4] = {};
    const int r0 = min(m0 + lrow, M - 1);
    const int r1 = min(m0 + 16 + lrow, M - 1);

    for (int k0 = 0; k0 < K; k0 += 32) {
        const int kk = k0 + lq * 8;
        half8 a0 = __builtin_nontemporal_load((const half8*)(A + (size_t)r0 * K + kk));
        half8 a1 = __builtin_nontemporal_load((const half8*)(A + (size_t)r1 * K + kk));
        half8 b[4];
#pragma unroll
        for (int j = 0; j < 4; j++)
            b[j] = *(const half8*)(&Ws[(j * 16 + lrow) * LDW + kk]);
#pragma unroll
        for (int j = 0; j < 4; j++) {
            acc[0][j] = __builtin_amdgcn_mfma_f32_16x16x32_f16(a0, b[j], acc[0][j], 0, 0, 0);
            acc[1][j] = __builtin_amdgcn_mfma_f32_16x16x32_f16(a1, b[j], acc[1][j], 0, 0, 0);
        }
    }

#pragma unroll
    for (int sub = 0; sub < 2; sub++) {
#pragma unroll
        for (int i = 0; i < 4; i++) {
            const int gm = m0 + sub * 16 + lq * 4 + i;
            if (gm < M) {
                const int gi = min(batch[gm] - g0, 5);
#pragma unroll
                for (int j = 0; j < 4; j++) {
                    const int gn = bn + j * 16 + lrow;
                    float v = acc[sub][j][i] + bias[gn];
                    v = fmaxf(v, 0.0f);
                    atomicAdd(&pl[gi][j * 16 + lrow], v);
                }
            }
        }
    }
    __syncthreads();

    for (int i = tid; i < 6 * 64; i += 256) {
        const int s = i >> 6, col = i & 63;
        const float v = pl[s][col];
        const int gg = g0 + s;
        if (v != 0.0f && gg < NG)
            atomicAdd(&pooled[(size_t)gg * HIDC + bn + col], v);
    }
}

__device__ __forceinline__ int lower_bound_batch(const int* __restrict__ batch, int val) {
    int lo = 0, hi = NN;
    while (lo < hi) {
        int mid = (lo + hi) >> 1;
        if (batch[mid] < val) lo = mid + 1;
        else hi = mid;
    }
    return lo;
}

// ---- head: mean + linear from pooled numerators ----
__global__ __launch_bounds__(256) void head_kernel(const float* __restrict__ pooled,
                                                   const int* __restrict__ batch,
                                                   const float* __restrict__ Wl,
                                                   const float* __restrict__ bl,
                                                   float* __restrict__ out) {
    __shared__ float s[HIDC];
    __shared__ float s2[OUTC][8];
    const int g = blockIdx.x;
    const int t = threadIdx.x;
    const int lo = lower_bound_batch(batch, g);
    const int hi = lower_bound_batch(batch, g + 1);
    const float inv = 1.0f / fmaxf((float)(hi - lo), 1.0f);
    if (t < HIDC) s[t] = pooled[(size_t)g * HIDC + t] * inv;
    __syncthreads();

    if (t < OUTC * 8) {
        const int oc = t >> 3, q = t & 7;
        float acc = 0.f;
        for (int k = q * 32; k < q * 32 + 32; k++)
            acc += s[k] * Wl[(size_t)oc * HIDC + k];
        s2[oc][q] = acc;
    }
    __syncthreads();
    if (t < OUTC) {
        float acc = bl[t];
#pragma unroll
        for (int q = 0; q < 8; q++) acc += s2[t][q];
        out[(size_t)g * OUTC + t] = acc;
    }
}

extern "C" void kernel_launch(void* const* d_in, const int* in_sizes, int n_in,
                              void* d_out, int out_size, void* d_ws, size_t ws_size,
                              hipStream_t stream) {
    const float* x     = (const float*)d_in[0];
    const int*   ei    = (const int*)d_in[1];
    const int*   batch = (const int*)d_in[2];
    const float* ew    = (const float*)d_in[3];
    const float* W1    = (const float*)d_in[4];
    const float* b1    = (const float*)d_in[5];
    const float* W2    = (const float*)d_in[6];
    const float* b2    = (const float*)d_in[7];
    const float* W3    = (const float*)d_in[8];
    const float* b3    = (const float*)d_in[9];
    const float* Wl    = (const float*)d_in[10];
    const float* bl    = (const float*)d_in[11];

    // ---- workspace layout (~21 MB) ----
    char* p = (char*)d_ws;
    ushort* xh     = (ushort*)p; p += (size_t)NN * INC * 2;
    ushort* agg128 = (ushort*)p; p += (size_t)NN * INC * 2;
    ushort* agg256 = (ushort*)p; p += (size_t)NN * HIDC * 2;
    ushort* h      = (ushort*)p; p += (size_t)NN * HIDC * 2;
    ushort* w1h    = (ushort*)p; p += (size_t)HIDC * INC * 2;
    ushort* w2h    = (ushort*)p; p += (size_t)HIDC * HIDC * 2;
    ushort* w3h    = (ushort*)p; p += (size_t)HIDC * HIDC * 2;
    uint*   erec   = (uint*)p;   p += (size_t)NN * DCAP * 4;
    int*    deg    = (int*)p;    p += (size_t)NN * 4;
    float*  pooled = (float*)p;  p += (size_t)NG * HIDC * 4;
    int*    qctr   = (int*)p;    p += 128;

    // ---- CSR build ----
    zero_kernel<<<32, 256, 0, stream>>>(deg, pooled, qctr);
    build_kernel<<<NRG * SLICES, 1024, 0, stream>>>(ei, ew, deg, erec, x, xh,
                                                    W1, w1h, W2, w2h, W3, w3h);

    dim3 gemm_grid((NN + 127) / 128, HIDC / 64);

    // ---- layer 1 (K=128, 2 slices) ----
    gatherq_kernel<INC, 2><<<GBLK, 256, 0, stream>>>(deg, erec, xh, agg128, qctr + 0);
    mfma_gemm_kernel<INC><<<gemm_grid, 256, 0, stream>>>(agg128, w1h, b1, h, NN);

    // ---- layer 2 (K=256, 4 slices) ----
    gatherq_kernel<HIDC, 4><<<GBLK, 256, 0, stream>>>(deg, erec, h, agg256, qctr + 8);
    mfma_gemm_kernel<HIDC><<<gemm_grid, 256, 0, stream>>>(agg256, w2h, b2, h, NN);

    // ---- layer 3 (K=256, 4 slices): gather then GEMM with fused mean-pool ----
    gatherq_kernel<HIDC, 4><<<GBLK, 256, 0, stream>>>(deg, erec, h, agg256, qctr + 16);
    mfma_gemm_pool_kernel<<<gemm_grid, 256, 0, stream>>>(agg256, w3h, b3, batch, pooled, NN);

    // ---- head ----
    head_kernel<<<NG, 256, 0, stream>>>(pooled, batch, Wl, bl, (float*)d_out);
}

// Round 8
// 239.664 us; speedup vs baseline: 2.9339x; 2.9339x over previous
//
#include <hip/hip_runtime.h>
#include <hip/hip_fp16.h>

namespace {
constexpr int NN   = 10000;   // nodes
constexpr int NE   = 640000;  // edges
constexpr int INC  = 128;     // input channels
constexpr int HIDC = 256;     // hidden channels
constexpr int OUTC = 10;      // output channels
constexpr int NG   = 64;      // graphs
constexpr int DCAP = 128;     // per-node edge-slot cap (deg mean 64, sigma 8 -> 8-sigma bound)
constexpr int NRG  = 8;       // dst ranges for build (XCD heuristic)
constexpr int RNG  = NN / NRG;      // 1250 nodes per range
constexpr int SLICES = 32;          // edge slices for build
constexpr int EPSL   = NE / SLICES; // 20000 edges per slice
}

typedef __attribute__((ext_vector_type(8))) _Float16 half8;
typedef __attribute__((ext_vector_type(4))) float f32x4;
typedef __attribute__((ext_vector_type(4))) ushort u16x4;

__device__ __forceinline__ ushort f2h(float f) { return __half_as_ushort(__float2half(f)); }
__device__ __forceinline__ float h2f(ushort u) { return __half2float(__ushort_as_half(u)); }

// ---- zero deg cursors + pooled accumulator ----
__global__ __launch_bounds__(256) void zero_kernel(int* __restrict__ deg,
                                                   float* __restrict__ pooled) {
    const int gt = blockIdx.x * 256 + threadIdx.x;
    const int gs = gridDim.x * 256;
    for (int i = gt; i < NN; i += gs) deg[i] = 0;
    for (int i = gt; i < NG * HIDC; i += gs) pooled[i] = 0.0f;
}

// ---- build: dst-range-partitioned two-scan counting scatter (proven round 4) ----
__global__ __launch_bounds__(1024) void build_kernel(const int* __restrict__ ei,
                                                     const float* __restrict__ ew,
                                                     int* __restrict__ deg,
                                                     uint* __restrict__ erec,
                                                     const float* __restrict__ x,
                                                     ushort* __restrict__ xh,
                                                     const float* __restrict__ W1,
                                                     ushort* __restrict__ w1h,
                                                     const float* __restrict__ W2,
                                                     ushort* __restrict__ w2h,
                                                     const float* __restrict__ W3,
                                                     ushort* __restrict__ w3h) {
    __shared__ int hist[RNG];
    const int t = threadIdx.x;
    const int rx = blockIdx.x & (NRG - 1);
    const int s  = blockIdx.x >> 3;
    const int nlo = rx * RNG;
    const int ebase = s * EPSL;

    for (int i = t; i < RNG; i += 1024) hist[i] = 0;
    __syncthreads();

    for (int vi = t * 4; vi < EPSL; vi += 4096) {
        const int4 d4 = *(const int4*)(ei + NE + ebase + vi);
        int rl;
        rl = d4.x - nlo; if ((uint)rl < (uint)RNG) atomicAdd(&hist[rl], 1);
        rl = d4.y - nlo; if ((uint)rl < (uint)RNG) atomicAdd(&hist[rl], 1);
        rl = d4.z - nlo; if ((uint)rl < (uint)RNG) atomicAdd(&hist[rl], 1);
        rl = d4.w - nlo; if ((uint)rl < (uint)RNG) atomicAdd(&hist[rl], 1);
    }
    __syncthreads();

    for (int b = t; b < RNG; b += 1024) {
        const int c = hist[b];
        if (c > 0) hist[b] = atomicAdd(&deg[nlo + b], c);
    }
    __syncthreads();

    for (int vi = t * 4; vi < EPSL; vi += 4096) {
        const int4 s4 = *(const int4*)(ei + ebase + vi);
        const int4 d4 = *(const int4*)(ei + NE + ebase + vi);
        const float4 w4 = *(const float4*)(ew + ebase + vi);
        int rl;
        rl = d4.x - nlo;
        if ((uint)rl < (uint)RNG) {
            const int idx = atomicAdd(&hist[rl], 1);
            if (idx < DCAP) erec[((size_t)(nlo + rl) << 7) + idx] = ((uint)s4.x << 16) | f2h(w4.x);
        }
        rl = d4.y - nlo;
        if ((uint)rl < (uint)RNG) {
            const int idx = atomicAdd(&hist[rl], 1);
            if (idx < DCAP) erec[((size_t)(nlo + rl) << 7) + idx] = ((uint)s4.y << 16) | f2h(w4.y);
        }
        rl = d4.z - nlo;
        if ((uint)rl < (uint)RNG) {
            const int idx = atomicAdd(&hist[rl], 1);
            if (idx < DCAP) erec[((size_t)(nlo + rl) << 7) + idx] = ((uint)s4.z << 16) | f2h(w4.z);
        }
        rl = d4.w - nlo;
        if ((uint)rl < (uint)RNG) {
            const int idx = atomicAdd(&hist[rl], 1);
            if (idx < DCAP) erec[((size_t)(nlo + rl) << 7) + idx] = ((uint)s4.w << 16) | f2h(w4.w);
        }
    }

    // conversion tail: fp32 -> fp16 of x and W1/W2/W3 (grid-stride, all blocks)
    const int gt = blockIdx.x * 1024 + t;
    const int gs = 256 * 1024;
    {
        const int n4 = NN * INC / 4;
        for (int i = gt; i < n4; i += gs) {
            f32x4 v = __builtin_nontemporal_load((const f32x4*)x + i);
            u16x4 o;
#pragma unroll
            for (int j = 0; j < 4; j++) o[j] = f2h(v[j]);
            __builtin_nontemporal_store(o, (u16x4*)xh + i);
        }
    }
    {
        const int n4 = HIDC * INC / 4;
        for (int i = gt; i < n4; i += gs) {
            f32x4 v = __builtin_nontemporal_load((const f32x4*)W1 + i);
            u16x4 o;
#pragma unroll
            for (int j = 0; j < 4; j++) o[j] = f2h(v[j]);
            __builtin_nontemporal_store(o, (u16x4*)w1h + i);
        }
    }
    {
        const int n4 = HIDC * HIDC / 4;
        for (int i = gt; i < n4; i += gs) {
            f32x4 v = __builtin_nontemporal_load((const f32x4*)W2 + i);
            u16x4 o;
#pragma unroll
            for (int j = 0; j < 4; j++) o[j] = f2h(v[j]);
            __builtin_nontemporal_store(o, (u16x4*)w2h + i);
            f32x4 v3 = __builtin_nontemporal_load((const f32x4*)W3 + i);
            u16x4 o3;
#pragma unroll
            for (int j = 0; j < 4; j++) o3[j] = f2h(v3[j]);
            __builtin_nontemporal_store(o3, (u16x4*)w3h + i);
        }
    }
}

// ---- gather: ONE wave = one node, ONE request per edge (full row).
// K=256: lane covers 4 ch (u16x4, 8 B) -> 512 B/request. K=128: lane covers
// 2 ch (uint, 4 B) -> 256 B/request. erec fetched as uint4 broadcasts
// (beg = n<<7 is 16B-aligned). U=8 edges in flight; fp32 accumulate. ----
template <int K>
__global__ __launch_bounds__(256) void gather_full_kernel(const int* __restrict__ deg,
                                                          const uint* __restrict__ erec,
                                                          const ushort* __restrict__ X,
                                                          ushort* __restrict__ out) {
    constexpr int CPL = K / 64;   // channels per lane (4 or 2)
    constexpr int U = 8;          // edges in flight
    const int n = blockIdx.x * 4 + (threadIdx.x >> 6);
    if (n >= NN) return;
    const int lane = threadIdx.x & 63;
    const int d = min(deg[n], DCAP);
    const int beg = n << 7;
    const size_t coff = (size_t)lane * CPL;
    const ushort* xr = X + coff;

    float a[CPL];
    {   // (1+eps)*x self term
        if constexpr (CPL == 4) {
            u16x4 v = *(const u16x4*)(X + (size_t)n * K + coff);
#pragma unroll
            for (int i = 0; i < 4; i++) a[i] = h2f(v[i]);
        } else {
            const uint v = *(const uint*)(X + (size_t)n * K + coff);
            a[0] = h2f((ushort)(v & 0xFFFFu));
            a[1] = h2f((ushort)(v >> 16));
        }
    }

    int e = 0;
    for (; e + U <= d; e += U) {
        const uint4 ra = *(const uint4*)(erec + beg + e);
        const uint4 rb = *(const uint4*)(erec + beg + e + 4);
        const uint rec[U] = {ra.x, ra.y, ra.z, ra.w, rb.x, rb.y, rb.z, rb.w};
        ushort v[U][CPL];
#pragma unroll
        for (int u = 0; u < U; u++) {
            if constexpr (CPL == 4)
                *(u16x4*)v[u] = *(const u16x4*)(xr + (size_t)(rec[u] >> 16) * K);
            else
                *(uint*)v[u] = *(const uint*)(xr + (size_t)(rec[u] >> 16) * K);
        }
#pragma unroll
        for (int u = 0; u < U; u++) {
            const float w = h2f((ushort)(rec[u] & 0xFFFFu));
#pragma unroll
            for (int i = 0; i < CPL; i++) a[i] += w * h2f(v[u][i]);
        }
    }
    for (; e < d; e++) {
        const uint rec = erec[beg + e];
        const float w = h2f((ushort)(rec & 0xFFFFu));
        ushort v[CPL];
        if constexpr (CPL == 4)
            *(u16x4*)v = *(const u16x4*)(xr + (size_t)(rec >> 16) * K);
        else
            *(uint*)v = *(const uint*)(xr + (size_t)(rec >> 16) * K);
#pragma unroll
        for (int i = 0; i < CPL; i++) a[i] += w * h2f(v[i]);
    }

    if constexpr (CPL == 4) {
        u16x4 o;
#pragma unroll
        for (int i = 0; i < 4; i++) o[i] = f2h(a[i]);
        *(u16x4*)(out + (size_t)n * K + coff) = o;       // keep in L2 for GEMM
    } else {
        const uint o = (uint)f2h(a[0]) | ((uint)f2h(a[1]) << 16);
        *(uint*)(out + (size_t)n * K + coff) = o;
    }
}

// ---- MFMA fp16 GEMM: C[M,256] = relu(A[M,K] @ W[256,K]^T + bias), fp16 out ----
template <int K>
__global__ __launch_bounds__(256) void mfma_gemm_kernel(const ushort* __restrict__ A,
                                                        const ushort* __restrict__ Wb,
                                                        const float* __restrict__ bias,
                                                        ushort* __restrict__ C, int M) {
    constexpr int LDW = K + 8;
    __shared__ ushort Ws[64 * LDW];
    const int tid = threadIdx.x;
    const int bm = blockIdx.x * 128;
    const int bn = blockIdx.y * 64;

    constexpr int CPR = K / 8;
    for (int idx = tid; idx < 64 * CPR; idx += 256) {
        int r = idx / CPR, c = idx % CPR;
        uint4 v = *(const uint4*)(Wb + (size_t)(bn + r) * K + c * 8);
        *(uint4*)(&Ws[r * LDW + c * 8]) = v;
    }
    __syncthreads();

    const int wave = tid >> 6;
    const int lane = tid & 63;
    const int lrow = lane & 15;
    const int lq   = lane >> 4;
    const int m0 = bm + wave * 32;

    f32x4 acc[2][4] = {};
    const int r0 = min(m0 + lrow, M - 1);
    const int r1 = min(m0 + 16 + lrow, M - 1);

    for (int k0 = 0; k0 < K; k0 += 32) {
        const int kk = k0 + lq * 8;
        half8 a0 = *(const half8*)(A + (size_t)r0 * K + kk);   // A is L2-hot
        half8 a1 = *(const half8*)(A + (size_t)r1 * K + kk);
        half8 b[4];
#pragma unroll
        for (int j = 0; j < 4; j++)
            b[j] = *(const half8*)(&Ws[(j * 16 + lrow) * LDW + kk]);
#pragma unroll
        for (int j = 0; j < 4; j++) {
            acc[0][j] = __builtin_amdgcn_mfma_f32_16x16x32_f16(a0, b[j], acc[0][j], 0, 0, 0);
            acc[1][j] = __builtin_amdgcn_mfma_f32_16x16x32_f16(a1, b[j], acc[1][j], 0, 0, 0);
        }
    }

#pragma unroll
    for (int sub = 0; sub < 2; sub++) {
#pragma unroll
        for (int j = 0; j < 4; j++) {
            const int gn = bn + j * 16 + lrow;
            const float bv = bias[gn];
#pragma unroll
            for (int i = 0; i < 4; i++) {
                const int gm = m0 + sub * 16 + lq * 4 + i;
                if (gm < M) {
                    float v = acc[sub][j][i] + bv;
                    v = fmaxf(v, 0.0f);
                    C[(size_t)gm * HIDC + gn] = f2h(v);
                }
            }
        }
    }
}

// ---- layer-3 GEMM with fused mean-pool numerators (no h store) ----
__global__ __launch_bounds__(256) void mfma_gemm_pool_kernel(const ushort* __restrict__ A,
                                                             const ushort* __restrict__ Wb,
                                                             const float* __restrict__ bias,
                                                             const int* __restrict__ batch,
                                                             float* __restrict__ pooled, int M) {
    constexpr int K = HIDC;
    constexpr int LDW = K + 8;
    __shared__ ushort Ws[64 * LDW];
    __shared__ float pl[6][64];
    const int tid = threadIdx.x;
    const int bm = blockIdx.x * 128;
    const int bn = blockIdx.y * 64;

    constexpr int CPR = K / 8;
    for (int idx = tid; idx < 64 * CPR; idx += 256) {
        int r = idx / CPR, c = idx % CPR;
        uint4 v = *(const uint4*)(Wb + (size_t)(bn + r) * K + c * 8);
        *(uint4*)(&Ws[r * LDW + c * 8]) = v;
    }
    for (int i = tid; i < 6 * 64; i += 256) pl[i >> 6][i & 63] = 0.0f;
    __syncthreads();

    const int wave = tid >> 6;
    const int lane = tid & 63;
    const int lrow = lane & 15;
    const int lq   = lane >> 4;
    const int m0 = bm + wave * 32;
    const int g0 = batch[bm];

    f32x4 acc[2][4] = {};
    const int r0 = min(m0 + lrow, M - 1);
    const int r1 = min(m0 + 16 + lrow, M - 1);

    for (int k0 = 0; k0 < K; k0 += 32) {
        const int kk = k0 + lq * 8;
        half8 a0 = *(const half8*)(A + (size_t)r0 * K + kk);
        half8 a1 = *(const half8*)(A + (size_t)r1 * K + kk);
        half8 b[4];
#pragma unroll
        for (int j = 0; j < 4; j++)
            b[j] = *(const half8*)(&Ws[(j * 16 + lrow) * LDW + kk]);
#pragma unroll
        for (int j = 0; j < 4; j++) {
            acc[0][j] = __builtin_amdgcn_mfma_f32_16x16x32_f16(a0, b[j], acc[0][j], 0, 0, 0);
            acc[1][j] = __builtin_amdgcn_mfma_f32_16x16x32_f16(a1, b[j], acc[1][j], 0, 0, 0);
        }
    }

#pragma unroll
    for (int sub = 0; sub < 2; sub++) {
#pragma unroll
        for (int i = 0; i < 4; i++) {
            const int gm = m0 + sub * 16 + lq * 4 + i;
            if (gm < M) {
                const int gi = min(batch[gm] - g0, 5);
#pragma unroll
                for (int j = 0; j < 4; j++) {
                    const int gn = bn + j * 16 + lrow;
                    float v = acc[sub][j][i] + bias[gn];
                    v = fmaxf(v, 0.0f);
                    atomicAdd(&pl[gi][j * 16 + lrow], v);
                }
            }
        }
    }
    __syncthreads();

    for (int i = tid; i < 6 * 64; i += 256) {
        const int s = i >> 6, col = i & 63;
        const float v = pl[s][col];
        const int gg = g0 + s;
        if (v != 0.0f && gg < NG)
            atomicAdd(&pooled[(size_t)gg * HIDC + bn + col], v);
    }
}

__device__ __forceinline__ int lower_bound_batch(const int* __restrict__ batch, int val) {
    int lo = 0, hi = NN;
    while (lo < hi) {
        int mid = (lo + hi) >> 1;
        if (batch[mid] < val) lo = mid + 1;
        else hi = mid;
    }
    return lo;
}

// ---- head: mean + linear from pooled numerators ----
__global__ __launch_bounds__(256) void head_kernel(const float* __restrict__ pooled,
                                                   const int* __restrict__ batch,
                                                   const float* __restrict__ Wl,
                                                   const float* __restrict__ bl,
                                                   float* __restrict__ out) {
    __shared__ float s[HIDC];
    __shared__ float s2[OUTC][8];
    const int g = blockIdx.x;
    const int t = threadIdx.x;
    const int lo = lower_bound_batch(batch, g);
    const int hi = lower_bound_batch(batch, g + 1);
    const float inv = 1.0f / fmaxf((float)(hi - lo), 1.0f);
    if (t < HIDC) s[t] = pooled[(size_t)g * HIDC + t] * inv;
    __syncthreads();

    if (t < OUTC * 8) {
        const int oc = t >> 3, q = t & 7;
        float acc = 0.f;
        for (int k = q * 32; k < q * 32 + 32; k++)
            acc += s[k] * Wl[(size_t)oc * HIDC + k];
        s2[oc][q] = acc;
    }
    __syncthreads();
    if (t < OUTC) {
        float acc = bl[t];
#pragma unroll
        for (int q = 0; q < 8; q++) acc += s2[t][q];
        out[(size_t)g * OUTC + t] = acc;
    }
}

extern "C" void kernel_launch(void* const* d_in, const int* in_sizes, int n_in,
                              void* d_out, int out_size, void* d_ws, size_t ws_size,
                              hipStream_t stream) {
    const float* x     = (const float*)d_in[0];
    const int*   ei    = (const int*)d_in[1];
    const int*   batch = (const int*)d_in[2];
    const float* ew    = (const float*)d_in[3];
    const float* W1    = (const float*)d_in[4];
    const float* b1    = (const float*)d_in[5];
    const float* W2    = (const float*)d_in[6];
    const float* b2    = (const float*)d_in[7];
    const float* W3    = (const float*)d_in[8];
    const float* b3    = (const float*)d_in[9];
    const float* Wl    = (const float*)d_in[10];
    const float* bl    = (const float*)d_in[11];

    // ---- workspace layout (~21 MB) ----
    char* p = (char*)d_ws;
    ushort* xh     = (ushort*)p; p += (size_t)NN * INC * 2;
    ushort* agg128 = (ushort*)p; p += (size_t)NN * INC * 2;
    ushort* agg256 = (ushort*)p; p += (size_t)NN * HIDC * 2;
    ushort* h      = (ushort*)p; p += (size_t)NN * HIDC * 2;
    ushort* w1h    = (ushort*)p; p += (size_t)HIDC * INC * 2;
    ushort* w2h    = (ushort*)p; p += (size_t)HIDC * HIDC * 2;
    ushort* w3h    = (ushort*)p; p += (size_t)HIDC * HIDC * 2;
    uint*   erec   = (uint*)p;   p += (size_t)NN * DCAP * 4;
    int*    deg    = (int*)p;    p += (size_t)NN * 4;
    float*  pooled = (float*)p;  p += (size_t)NG * HIDC * 4;

    // ---- CSR build ----
    zero_kernel<<<32, 256, 0, stream>>>(deg, pooled);
    build_kernel<<<NRG * SLICES, 1024, 0, stream>>>(ei, ew, deg, erec, x, xh,
                                                    W1, w1h, W2, w2h, W3, w3h);

    const int gather_grid = (NN + 3) / 4;
    dim3 gemm_grid((NN + 127) / 128, HIDC / 64);

    // ---- layer 1 (K=128) ----
    gather_full_kernel<INC><<<gather_grid, 256, 0, stream>>>(deg, erec, xh, agg128);
    mfma_gemm_kernel<INC><<<gemm_grid, 256, 0, stream>>>(agg128, w1h, b1, h, NN);

    // ---- layer 2 (K=256) ----
    gather_full_kernel<HIDC><<<gather_grid, 256, 0, stream>>>(deg, erec, h, agg256);
    mfma_gemm_kernel<HIDC><<<gemm_grid, 256, 0, stream>>>(agg256, w2h, b2, h, NN);

    // ---- layer 3 (K=256): gather then GEMM with fused mean-pool ----
    gather_full_kernel<HIDC><<<gather_grid, 256, 0, stream>>>(deg, erec, h, agg256);
    mfma_gemm_pool_kernel<<<gemm_grid, 256, 0, stream>>>(agg256, w3h, b3, batch, pooled, NN);

    // ---- head ----
    head_kernel<<<NG, 256, 0, stream>>>(pooled, batch, Wl, bl, (float*)d_out);
}